// Round 5
// baseline (9651.144 us; speedup 1.0000x reference)
//
#include <hip/hip_runtime.h>
#include <math.h>

// ---------------------------------------------------------------------------
// Round 5: fp64 quant-decision + fp64 score path (theory A killer).
//   All fake_quant decisions: q = rint(double(x)/double(s)), s = max/127.0 in
//   double (matches a float64 numpy golden bit-for-bit at round boundaries).
//   Scores, softmax, PV in float64 -> argmax/blend identical to an f64 ref.
//   Structure otherwise identical to R4's audited VALU build.
//   B=4, T=2048, D=512, H=8, dk=64.  fp32 in / fp32 out.  ws ~42 MB.
// ---------------------------------------------------------------------------

// ---------------------------------------------------------------------------
// Kernel 1: per-token abs-max scale (double).  s[t]=max(max|x[:,t,:]|/127,1e-8)
// grid (2048, nz), block 256.
// ---------------------------------------------------------------------------
__global__ __launch_bounds__(256) void token_scale(
    const float* __restrict__ x0, const float* __restrict__ x1,
    const float* __restrict__ x2, double* __restrict__ out)
{
    const int t = blockIdx.x;
    const int z = blockIdx.y;
    const float* __restrict__ x = (z == 0) ? x0 : ((z == 1) ? x1 : x2);
    const int tid = threadIdx.x;
    float m = 0.0f;
#pragma unroll
    for (int i = 0; i < 2; ++i) {
        int f = i * 256 + tid;          // [0,512) float4 slots over 4 batch rows
        int b = f >> 7, d4 = f & 127;
        float4 v = *(const float4*)(x + (long)(b * 2048 + t) * 512 + d4 * 4);
        m = fmaxf(m, fmaxf(fmaxf(fabsf(v.x), fabsf(v.y)), fmaxf(fabsf(v.z), fabsf(v.w))));
    }
#pragma unroll
    for (int off = 1; off < 64; off <<= 1) m = fmaxf(m, __shfl_xor(m, off));
    __shared__ float red[4];
    if ((tid & 63) == 0) red[tid >> 6] = m;
    __syncthreads();
    if (tid == 0) {
        m = fmaxf(fmaxf(red[0], red[1]), fmaxf(red[2], red[3]));
        out[z * 2048 + t] = fmax((double)m / 127.0, 1e-8);   // f64 div + clamp
    }
}

// ---------------------------------------------------------------------------
// Kernel 2: weight quantization (double decisions).  One thread per column.
// qW stored [n][k] as fp16 (integers |q|<=128: exact).  grid (2,3), block 256.
// ---------------------------------------------------------------------------
__global__ __launch_bounds__(256) void wquant(
    const float* __restrict__ Wq, const float* __restrict__ Wk,
    const float* __restrict__ Wv, double* __restrict__ sw,
    _Float16* __restrict__ qW)
{
    const int z = blockIdx.y;
    const float* __restrict__ W = (z == 0) ? Wq : (z == 1) ? Wk : Wv;
    const int col = blockIdx.x * 256 + threadIdx.x;   // [0,512)
    float m = 0.0f;
    for (int k = 0; k < 512; ++k) m = fmaxf(m, fabsf(W[k * 512 + col]));
    const double s = fmax((double)m / 127.0, 1e-8);
    sw[z * 512 + col] = s;
    _Float16* q = qW + (long)z * 262144 + (long)col * 512;
    for (int k = 0; k < 512; ++k)
        q[k] = (_Float16)fmin(fmax(rint((double)W[k * 512 + col] / s), -128.0), 127.0);
}

// ---------------------------------------------------------------------------
// Kernel 3: projection GEMM.  Integer GEMM exact in fp32; quant decisions in
// f64; outputs Q,K,V planes as f64 exact dequant I*sa*sw, layout [h][t][d].
// grid (32, 8, 3), block 256.  One batch per launch.
// ---------------------------------------------------------------------------
__global__ __launch_bounds__(256) void proj_valu(
    const float* __restrict__ q_in, const float* __restrict__ k_in,
    const float* __restrict__ v_in, const double* __restrict__ saAll,
    const _Float16* __restrict__ qW, const double* __restrict__ swAll,
    double* __restrict__ Qb, double* __restrict__ Kb, double* __restrict__ Vb,
    int b)
{
    const int z = blockIdx.z;
    const float* __restrict__ A = (z == 0) ? q_in : (z == 1) ? k_in : v_in;
    const double* __restrict__ sa = saAll + z * 2048;
    const _Float16* __restrict__ Bq = qW + (long)z * 262144;
    const double* __restrict__ swz = swAll + z * 512;
    double* __restrict__ O = (z == 0) ? Qb : (z == 1) ? Kb : Vb;

    const int m0 = blockIdx.x * 64, n0 = blockIdx.y * 64;
    const int tid = threadIdx.x, ty = tid >> 4, tx = tid & 15;

    __shared__ float As[64 * 33];
    __shared__ float Bs[64 * 33];

    float acc[4][4] = {{0.f,0.f,0.f,0.f},{0.f,0.f,0.f,0.f},
                       {0.f,0.f,0.f,0.f},{0.f,0.f,0.f,0.f}};

    for (int k0 = 0; k0 < 512; k0 += 32) {
        if (k0) __syncthreads();
#pragma unroll
        for (int i = 0; i < 2; ++i) {
            int slot = i * 256 + tid;                 // [0,512)
            int row = slot >> 3, q4 = slot & 7;
            int t = m0 + row;
            float4 v = *(const float4*)(A + ((long)(b * 2048 + t)) * 512 + k0 + q4 * 4);
            double s = sa[t];
            As[row * 33 + q4 * 4 + 0] = (float)fmin(fmax(rint((double)v.x / s), -128.0), 127.0);
            As[row * 33 + q4 * 4 + 1] = (float)fmin(fmax(rint((double)v.y / s), -128.0), 127.0);
            As[row * 33 + q4 * 4 + 2] = (float)fmin(fmax(rint((double)v.z / s), -128.0), 127.0);
            As[row * 33 + q4 * 4 + 3] = (float)fmin(fmax(rint((double)v.w / s), -128.0), 127.0);
            const _Float16* wp = Bq + (long)(n0 + row) * 512 + k0 + q4 * 4;
            Bs[row * 33 + q4 * 4 + 0] = (float)wp[0];
            Bs[row * 33 + q4 * 4 + 1] = (float)wp[1];
            Bs[row * 33 + q4 * 4 + 2] = (float)wp[2];
            Bs[row * 33 + q4 * 4 + 3] = (float)wp[3];
        }
        __syncthreads();
        for (int kk = 0; kk < 32; ++kk) {
            float a[4], bb[4];
#pragma unroll
            for (int i = 0; i < 4; ++i) a[i] = As[(ty * 4 + i) * 33 + kk];
#pragma unroll
            for (int j = 0; j < 4; ++j) bb[j] = Bs[(tx * 4 + j) * 33 + kk];
#pragma unroll
            for (int i = 0; i < 4; ++i)
#pragma unroll
                for (int j = 0; j < 4; ++j) acc[i][j] += a[i] * bb[j];
        }
    }
#pragma unroll
    for (int i = 0; i < 4; ++i)
#pragma unroll
        for (int j = 0; j < 4; ++j) {
            int t = m0 + ty * 4 + i, n = n0 + tx * 4 + j;
            double val = (double)acc[i][j] * sa[t] * swz[n];   // exact int * f64
            int h = n >> 6, d = n & 63;
            O[((long)h * 2048 + t) * 64 + d] = val;
        }
}

// ---------------------------------------------------------------------------
// Kernel 4: attention, non-flash, FULL fp64.  One block per (t, h).
// grid (2048, 8), block 256.  LDS ~52 KB.
// ---------------------------------------------------------------------------
__global__ __launch_bounds__(256) void attn_valu(
    const double* __restrict__ Qb, const double* __restrict__ Kb,
    const double* __restrict__ Vb, float* __restrict__ xbuf, int b)
{
    const int t = blockIdx.x, h = blockIdx.y, tid = threadIdx.x;
    __shared__ double tile[64 * 65];
    __shared__ double Srow[2048];
    __shared__ double qrow[64];
    __shared__ double red[256];

    if (tid < 64) qrow[tid] = Qb[((long)h * 2048 + t) * 64 + tid];
    __syncthreads();

    // ---- phase 1: scores (f64) ----
    for (int kt = 0; kt < 32; ++kt) {
        if (kt) __syncthreads();
#pragma unroll
        for (int i = 0; i < 16; ++i) {
            int slot = i * 256 + tid;          // [0,4096)
            int row = slot >> 6, d = slot & 63;
            tile[row * 65 + d] = Kb[((long)h * 2048 + kt * 64 + row) * 64 + d];
        }
        __syncthreads();
        if (tid < 64) {
            double s = 0.0;
            for (int d = 0; d < 64; ++d) s += qrow[d] * tile[tid * 65 + d];
            Srow[kt * 64 + tid] = s * 0.125;
        }
    }
    __syncthreads();

    // ---- phase 2: softmax (two-pass, f64 exp) ----
    double pm = -1.0e300;
#pragma unroll
    for (int i = 0; i < 8; ++i) pm = fmax(pm, Srow[tid * 8 + i]);
    red[tid] = pm;
    __syncthreads();
    for (int st = 128; st > 0; st >>= 1) {
        if (tid < st) red[tid] = fmax(red[tid], red[tid + st]);
        __syncthreads();
    }
    const double mx = red[0];
    __syncthreads();
    double ps = 0.0;
#pragma unroll
    for (int i = 0; i < 8; ++i) {
        double p = exp(Srow[tid * 8 + i] - mx);
        Srow[tid * 8 + i] = p;
        ps += p;
    }
    red[tid] = ps;
    __syncthreads();
    for (int st = 128; st > 0; st >>= 1) {
        if (tid < st) red[tid] += red[tid + st];
        __syncthreads();
    }
    const double l = red[0];

    // ---- phase 3: PV (f64) ----
    double acc = 0.0;
    for (int kt = 0; kt < 32; ++kt) {
        __syncthreads();
#pragma unroll
        for (int i = 0; i < 16; ++i) {
            int slot = i * 256 + tid;
            int row = slot >> 6, d = slot & 63;
            tile[row * 65 + d] = Vb[((long)h * 2048 + kt * 64 + row) * 64 + d];
        }
        __syncthreads();
        if (tid < 64) {
            for (int k = 0; k < 64; ++k) acc += Srow[kt * 64 + k] * tile[k * 65 + tid];
        }
    }
    if (tid < 64)
        xbuf[((long)(b * 2048 + t)) * 512 + h * 64 + tid] = (float)(acc / l);
}

// ---------------------------------------------------------------------------
// Kernel 5: final GEMM.  Quant decision f64; integer GEMM fp32; out*sx (f64).
// grid (128, 8), block 256.
// ---------------------------------------------------------------------------
__global__ __launch_bounds__(256) void final_valu(
    const float* __restrict__ xbuf, const double* __restrict__ sx,
    const float* __restrict__ Wf, float* __restrict__ out)
{
    const int m0 = blockIdx.x * 64, n0 = blockIdx.y * 64;
    const int tid = threadIdx.x, ty = tid >> 4, tx = tid & 15;

    __shared__ float As[64 * 33];
    __shared__ float Bs[32 * 65];

    float acc[4][4] = {{0.f,0.f,0.f,0.f},{0.f,0.f,0.f,0.f},
                       {0.f,0.f,0.f,0.f},{0.f,0.f,0.f,0.f}};

    for (int k0 = 0; k0 < 512; k0 += 32) {
        if (k0) __syncthreads();
#pragma unroll
        for (int i = 0; i < 2; ++i) {
            int slot = i * 256 + tid;                 // [0,512)
            int row = slot >> 3, q4 = slot & 7;       // A: 64 rows x 8 float4
            int m = m0 + row;
            double s = sx[m & 2047];
            float4 v = *(const float4*)(xbuf + (long)m * 512 + k0 + q4 * 4);
            As[row * 33 + q4 * 4 + 0] = (float)fmin(fmax(rint((double)v.x / s), -128.0), 127.0);
            As[row * 33 + q4 * 4 + 1] = (float)fmin(fmax(rint((double)v.y / s), -128.0), 127.0);
            As[row * 33 + q4 * 4 + 2] = (float)fmin(fmax(rint((double)v.z / s), -128.0), 127.0);
            As[row * 33 + q4 * 4 + 3] = (float)fmin(fmax(rint((double)v.w / s), -128.0), 127.0);
            int krow = slot >> 4, n4 = slot & 15;     // B: 32 k x 16 float4
            float4 w4 = *(const float4*)(Wf + (long)(k0 + krow) * 512 + n0 + n4 * 4);
            Bs[krow * 65 + n4 * 4 + 0] = w4.x;
            Bs[krow * 65 + n4 * 4 + 1] = w4.y;
            Bs[krow * 65 + n4 * 4 + 2] = w4.z;
            Bs[krow * 65 + n4 * 4 + 3] = w4.w;
        }
        __syncthreads();
        for (int kk = 0; kk < 32; ++kk) {
            float a[4], bb[4];
#pragma unroll
            for (int i = 0; i < 4; ++i) a[i] = As[(ty * 4 + i) * 33 + kk];
#pragma unroll
            for (int j = 0; j < 4; ++j) bb[j] = Bs[kk * 65 + tx * 4 + j];
#pragma unroll
            for (int i = 0; i < 4; ++i)
#pragma unroll
                for (int j = 0; j < 4; ++j) acc[i][j] += a[i] * bb[j];
        }
    }
#pragma unroll
    for (int i = 0; i < 4; ++i)
#pragma unroll
        for (int j = 0; j < 4; ++j) {
            int m = m0 + ty * 4 + i, n = n0 + tx * 4 + j;
            out[(long)m * 512 + n] = (float)((double)acc[i][j] * sx[m & 2047]);
        }
}

// ---------------------------------------------------------------------------
extern "C" void kernel_launch(void* const* d_in, const int* in_sizes, int n_in,
                              void* d_out, int out_size, void* d_ws, size_t ws_size,
                              hipStream_t stream)
{
    const float* query = (const float*)d_in[0];
    const float* key_  = (const float*)d_in[1];
    const float* value = (const float*)d_in[2];
    const float* Wq = (const float*)d_in[3];
    const float* Wk = (const float*)d_in[4];
    const float* Wv = (const float*)d_in[5];
    const float* Wf = (const float*)d_in[6];
    float* out = (float*)d_out;

    // workspace carve-up: ~42 MB total
    char* p = (char*)d_ws;
    auto alloc = [&](size_t bytes) -> char* {
        char* r = p;
        p += (bytes + 255) & ~(size_t)255;
        return r;
    };
    double*   sA   = (double*)alloc(3 * 2048 * 8);
    double*   sx   = (double*)alloc(2048 * 8);
    double*   sw   = (double*)alloc(3 * 512 * 8);
    _Float16* qW   = (_Float16*)alloc((size_t)3 * 512 * 512 * 2);   // 1.5 MB
    double*   Qb   = (double*)alloc((size_t)2048 * 512 * 8);        // 8 MB
    double*   Kb   = (double*)alloc((size_t)2048 * 512 * 8);        // 8 MB
    double*   Vb   = (double*)alloc((size_t)2048 * 512 * 8);        // 8 MB
    float*    xbuf = (float*)alloc((size_t)8192 * 512 * 4);         // 16 MB

    token_scale<<<dim3(2048, 3), 256, 0, stream>>>(query, key_, value, sA);
    wquant<<<dim3(2, 3), 256, 0, stream>>>(Wq, Wk, Wv, sw, qW);
    for (int b = 0; b < 4; ++b) {
        proj_valu<<<dim3(32, 8, 3), 256, 0, stream>>>(query, key_, value, sA, qW, sw,
                                                      Qb, Kb, Vb, b);
        attn_valu<<<dim3(2048, 8), 256, 0, stream>>>(Qb, Kb, Vb, xbuf, b);
    }
    token_scale<<<dim3(2048, 1), 256, 0, stream>>>(xbuf, xbuf, xbuf, sx);
    final_valu<<<dim3(128, 8), 256, 0, stream>>>(xbuf, sx, Wf, out);
}

// Round 6
// 2493.083 us; speedup vs baseline: 3.8712x; 3.8712x over previous
//
#include <hip/hip_runtime.h>
#include <math.h>

// ---------------------------------------------------------------------------
// Round 6: same f64 numerics as the PASSING R5 build (absmax 54.0), with the
// attention kernel restructured for parallel efficiency (R5: 95% of runtime,
// VALUBusy 12.9%, 64/256 threads active).  All fake_quant decisions and the
// score/softmax/PV path remain f64 -- only summation order changes (~1e-13).
//   B=4, T=2048, D=512, H=8, dk=64.  fp32 in / fp32 out.  ws ~42 MB.
// ---------------------------------------------------------------------------

// ---------------------------------------------------------------------------
// Kernel 1: per-token abs-max scale (f64 decisions).  UNCHANGED from R5.
// ---------------------------------------------------------------------------
__global__ __launch_bounds__(256) void token_scale(
    const float* __restrict__ x0, const float* __restrict__ x1,
    const float* __restrict__ x2, double* __restrict__ out)
{
    const int t = blockIdx.x;
    const int z = blockIdx.y;
    const float* __restrict__ x = (z == 0) ? x0 : ((z == 1) ? x1 : x2);
    const int tid = threadIdx.x;
    float m = 0.0f;
#pragma unroll
    for (int i = 0; i < 2; ++i) {
        int f = i * 256 + tid;
        int b = f >> 7, d4 = f & 127;
        float4 v = *(const float4*)(x + (long)(b * 2048 + t) * 512 + d4 * 4);
        m = fmaxf(m, fmaxf(fmaxf(fabsf(v.x), fabsf(v.y)), fmaxf(fabsf(v.z), fabsf(v.w))));
    }
#pragma unroll
    for (int off = 1; off < 64; off <<= 1) m = fmaxf(m, __shfl_xor(m, off));
    __shared__ float red[4];
    if ((tid & 63) == 0) red[tid >> 6] = m;
    __syncthreads();
    if (tid == 0) {
        m = fmaxf(fmaxf(red[0], red[1]), fmaxf(red[2], red[3]));
        out[z * 2048 + t] = fmax((double)m / 127.0, 1e-8);
    }
}

// ---------------------------------------------------------------------------
// Kernel 2: weight quantization (f64 decisions).  UNCHANGED from R5.
// ---------------------------------------------------------------------------
__global__ __launch_bounds__(256) void wquant(
    const float* __restrict__ Wq, const float* __restrict__ Wk,
    const float* __restrict__ Wv, double* __restrict__ sw,
    _Float16* __restrict__ qW)
{
    const int z = blockIdx.y;
    const float* __restrict__ W = (z == 0) ? Wq : (z == 1) ? Wk : Wv;
    const int col = blockIdx.x * 256 + threadIdx.x;
    float m = 0.0f;
    for (int k = 0; k < 512; ++k) m = fmaxf(m, fabsf(W[k * 512 + col]));
    const double s = fmax((double)m / 127.0, 1e-8);
    sw[z * 512 + col] = s;
    _Float16* q = qW + (long)z * 262144 + (long)col * 512;
    for (int k = 0; k < 512; ++k)
        q[k] = (_Float16)fmin(fmax(rint((double)W[k * 512 + col] / s), -128.0), 127.0);
}

// ---------------------------------------------------------------------------
// Kernel 3: projection GEMM (exact-int fp32, f64 decisions + dequant).
// UNCHANGED from R5.
// ---------------------------------------------------------------------------
__global__ __launch_bounds__(256) void proj_valu(
    const float* __restrict__ q_in, const float* __restrict__ k_in,
    const float* __restrict__ v_in, const double* __restrict__ saAll,
    const _Float16* __restrict__ qW, const double* __restrict__ swAll,
    double* __restrict__ Qb, double* __restrict__ Kb, double* __restrict__ Vb,
    int b)
{
    const int z = blockIdx.z;
    const float* __restrict__ A = (z == 0) ? q_in : (z == 1) ? k_in : v_in;
    const double* __restrict__ sa = saAll + z * 2048;
    const _Float16* __restrict__ Bq = qW + (long)z * 262144;
    const double* __restrict__ swz = swAll + z * 512;
    double* __restrict__ O = (z == 0) ? Qb : (z == 1) ? Kb : Vb;

    const int m0 = blockIdx.x * 64, n0 = blockIdx.y * 64;
    const int tid = threadIdx.x, ty = tid >> 4, tx = tid & 15;

    __shared__ float As[64 * 33];
    __shared__ float Bs[64 * 33];

    float acc[4][4] = {{0.f,0.f,0.f,0.f},{0.f,0.f,0.f,0.f},
                       {0.f,0.f,0.f,0.f},{0.f,0.f,0.f,0.f}};

    for (int k0 = 0; k0 < 512; k0 += 32) {
        if (k0) __syncthreads();
#pragma unroll
        for (int i = 0; i < 2; ++i) {
            int slot = i * 256 + tid;
            int row = slot >> 3, q4 = slot & 7;
            int t = m0 + row;
            float4 v = *(const float4*)(A + ((long)(b * 2048 + t)) * 512 + k0 + q4 * 4);
            double s = sa[t];
            As[row * 33 + q4 * 4 + 0] = (float)fmin(fmax(rint((double)v.x / s), -128.0), 127.0);
            As[row * 33 + q4 * 4 + 1] = (float)fmin(fmax(rint((double)v.y / s), -128.0), 127.0);
            As[row * 33 + q4 * 4 + 2] = (float)fmin(fmax(rint((double)v.z / s), -128.0), 127.0);
            As[row * 33 + q4 * 4 + 3] = (float)fmin(fmax(rint((double)v.w / s), -128.0), 127.0);
            const _Float16* wp = Bq + (long)(n0 + row) * 512 + k0 + q4 * 4;
            Bs[row * 33 + q4 * 4 + 0] = (float)wp[0];
            Bs[row * 33 + q4 * 4 + 1] = (float)wp[1];
            Bs[row * 33 + q4 * 4 + 2] = (float)wp[2];
            Bs[row * 33 + q4 * 4 + 3] = (float)wp[3];
        }
        __syncthreads();
        for (int kk = 0; kk < 32; ++kk) {
            float a[4], bb[4];
#pragma unroll
            for (int i = 0; i < 4; ++i) a[i] = As[(ty * 4 + i) * 33 + kk];
#pragma unroll
            for (int j = 0; j < 4; ++j) bb[j] = Bs[(tx * 4 + j) * 33 + kk];
#pragma unroll
            for (int i = 0; i < 4; ++i)
#pragma unroll
                for (int j = 0; j < 4; ++j) acc[i][j] += a[i] * bb[j];
        }
    }
#pragma unroll
    for (int i = 0; i < 4; ++i)
#pragma unroll
        for (int j = 0; j < 4; ++j) {
            int t = m0 + ty * 4 + i, n = n0 + tx * 4 + j;
            double val = (double)acc[i][j] * sa[t] * swz[n];
            int h = n >> 6, d = n & 63;
            O[((long)h * 2048 + t) * 64 + d] = val;
        }
}

// ---------------------------------------------------------------------------
// Kernel 4: attention, f64, TILED (replaces R5's latency-bound attn_valu).
// grid (64 q-tiles of 32, 8 heads), block 256.  Per 32-key tile:
//   stage K,V [32][64] f64 -> LDS; S = QK^T/8 via 2x2 f64 register blocking;
//   online softmax (row threads: max/alpha; all threads: exp + partial sums);
//   O (2q x 4d f64 regs) rescale + PV via 2x4 blocking.
// LDS 62208 B.  Numerics: f64 throughout, same values as R5 modulo sum order.
// ---------------------------------------------------------------------------
__global__ __launch_bounds__(256) void attn_fast(
    const double* __restrict__ Qb, const double* __restrict__ Kb,
    const double* __restrict__ Vb, float* __restrict__ xbuf, int b)
{
    const int q0 = blockIdx.x * 32;
    const int h = blockIdx.y;
    const int tid = threadIdx.x;
    const int ty = tid >> 4, tx = tid & 15;        // 16x16 thread grid
    const int qr0 = ty * 2;                        // this thread's 2 q-rows
    const int srow = tid >> 3, sc0 = (tid & 7) * 4;// exp-phase mapping

    __shared__ double Qs[32 * 66];                 // [q][d]  stride 66 (b128-aligned)
    __shared__ double Ks[32 * 66];                 // [key][d]
    __shared__ double Vs[32 * 66];                 // [key][d]
    __shared__ double SP[32 * 34];                 // [q][key] scores -> p in place
    __shared__ double mS[32], lS[32], aS[32];
    __shared__ double psums[32 * 8];

    // ---- stage Q tile (once) + init stats ----
    {
        int row = tid >> 3, d8 = (tid & 7) * 8;
        const double* qp = Qb + ((long)h * 2048 + q0 + row) * 64 + d8;
#pragma unroll
        for (int j = 0; j < 4; ++j)
            *(double2*)&Qs[row * 66 + d8 + j * 2] = *(const double2*)(qp + j * 2);
    }
    if (tid < 32) { mS[tid] = -1.0e300; lS[tid] = 0.0; }

    double O[2][4] = {{0,0,0,0},{0,0,0,0}};

    for (int k0 = 0; k0 < 2048; k0 += 32) {
        __syncthreads();  // B1: prev tile's readers of Ks/Vs/SP done
        // ---- stage K and V tiles ----
        {
            int row = tid >> 3, d8 = (tid & 7) * 8;
            const double* kp = Kb + ((long)h * 2048 + k0 + row) * 64 + d8;
            const double* vp = Vb + ((long)h * 2048 + k0 + row) * 64 + d8;
#pragma unroll
            for (int j = 0; j < 4; ++j) {
                *(double2*)&Ks[row * 66 + d8 + j * 2] = *(const double2*)(kp + j * 2);
                *(double2*)&Vs[row * 66 + d8 + j * 2] = *(const double2*)(vp + j * 2);
            }
        }
        __syncthreads();  // B2: tiles visible

        // ---- S = QK^T / 8 : 2q x 2k per thread, f64 ----
        {
            const int kr0 = tx * 2;
            double a00 = 0, a01 = 0, a10 = 0, a11 = 0;
            for (int d = 0; d < 64; d += 2) {
                double2 qa0 = *(const double2*)&Qs[(qr0 + 0) * 66 + d];
                double2 qa1 = *(const double2*)&Qs[(qr0 + 1) * 66 + d];
                double2 kb0 = *(const double2*)&Ks[(kr0 + 0) * 66 + d];
                double2 kb1 = *(const double2*)&Ks[(kr0 + 1) * 66 + d];
                a00 += qa0.x * kb0.x + qa0.y * kb0.y;
                a01 += qa0.x * kb1.x + qa0.y * kb1.y;
                a10 += qa1.x * kb0.x + qa1.y * kb0.y;
                a11 += qa1.x * kb1.x + qa1.y * kb1.y;
            }
            SP[(qr0 + 0) * 34 + kr0 + 0] = a00 * 0.125;
            SP[(qr0 + 0) * 34 + kr0 + 1] = a01 * 0.125;
            SP[(qr0 + 1) * 34 + kr0 + 0] = a10 * 0.125;
            SP[(qr0 + 1) * 34 + kr0 + 1] = a11 * 0.125;
        }
        __syncthreads();  // B3: S visible

        // ---- row stats: rowmax, m_new, alpha ----
        if (tid < 32) {
            double rm = -1.0e300;
            for (int k = 0; k < 32; ++k) rm = fmax(rm, SP[tid * 34 + k]);
            double mold = mS[tid];
            double mn = fmax(mold, rm);
            aS[tid] = exp(mold - mn);
            mS[tid] = mn;
        }
        __syncthreads();  // B4: m_new / alpha visible

        // ---- exp phase (all threads) + O rescale ----
        {
            double mn = mS[srow];
            double sum = 0.0;
#pragma unroll
            for (int j = 0; j < 4; ++j) {
                double p = exp(SP[srow * 34 + sc0 + j] - mn);
                SP[srow * 34 + sc0 + j] = p;
                sum += p;
            }
            psums[srow * 8 + (tid & 7)] = sum;
            double a0 = aS[qr0], a1 = aS[qr0 + 1];
#pragma unroll
            for (int j = 0; j < 4; ++j) { O[0][j] *= a0; O[1][j] *= a1; }
        }
        __syncthreads();  // B5: P and psums visible

        // ---- l update (row threads; others go straight to PV) ----
        if (tid < 32) {
            double s = 0.0;
#pragma unroll
            for (int j = 0; j < 8; ++j) s += psums[tid * 8 + j];
            lS[tid] = lS[tid] * aS[tid] + s;
        }

        // ---- PV: O[2q][4d] += P * V ----
        {
            const int dc = tx * 4;
            for (int k = 0; k < 32; k += 2) {
                double2 p0 = *(const double2*)&SP[(qr0 + 0) * 34 + k];
                double2 p1 = *(const double2*)&SP[(qr0 + 1) * 34 + k];
                double2 va = *(const double2*)&Vs[(k + 0) * 66 + dc];
                double2 vb = *(const double2*)&Vs[(k + 0) * 66 + dc + 2];
                double2 vc = *(const double2*)&Vs[(k + 1) * 66 + dc];
                double2 vd = *(const double2*)&Vs[(k + 1) * 66 + dc + 2];
                O[0][0] += p0.x * va.x + p0.y * vc.x;
                O[0][1] += p0.x * va.y + p0.y * vc.y;
                O[0][2] += p0.x * vb.x + p0.y * vd.x;
                O[0][3] += p0.x * vb.y + p0.y * vd.y;
                O[1][0] += p1.x * va.x + p1.y * vc.x;
                O[1][1] += p1.x * va.y + p1.y * vc.y;
                O[1][2] += p1.x * vb.x + p1.y * vd.x;
                O[1][3] += p1.x * vb.y + p1.y * vd.y;
            }
        }
    }

    __syncthreads();  // final lS visible
    {
        double l0 = lS[qr0], l1 = lS[qr0 + 1];
        long base0 = ((long)(b * 2048 + q0 + qr0 + 0)) * 512 + h * 64 + tx * 4;
        long base1 = ((long)(b * 2048 + q0 + qr0 + 1)) * 512 + h * 64 + tx * 4;
#pragma unroll
        for (int j = 0; j < 4; ++j) {
            xbuf[base0 + j] = (float)(O[0][j] / l0);
            xbuf[base1 + j] = (float)(O[1][j] / l1);
        }
    }
}

// ---------------------------------------------------------------------------
// Kernel 5: final GEMM (f64 decisions, exact-int fp32 GEMM).  UNCHANGED.
// ---------------------------------------------------------------------------
__global__ __launch_bounds__(256) void final_valu(
    const float* __restrict__ xbuf, const double* __restrict__ sx,
    const float* __restrict__ Wf, float* __restrict__ out)
{
    const int m0 = blockIdx.x * 64, n0 = blockIdx.y * 64;
    const int tid = threadIdx.x, ty = tid >> 4, tx = tid & 15;

    __shared__ float As[64 * 33];
    __shared__ float Bs[32 * 65];

    float acc[4][4] = {{0.f,0.f,0.f,0.f},{0.f,0.f,0.f,0.f},
                       {0.f,0.f,0.f,0.f},{0.f,0.f,0.f,0.f}};

    for (int k0 = 0; k0 < 512; k0 += 32) {
        if (k0) __syncthreads();
#pragma unroll
        for (int i = 0; i < 2; ++i) {
            int slot = i * 256 + tid;
            int row = slot >> 3, q4 = slot & 7;
            int m = m0 + row;
            double s = sx[m & 2047];
            float4 v = *(const float4*)(xbuf + (long)m * 512 + k0 + q4 * 4);
            As[row * 33 + q4 * 4 + 0] = (float)fmin(fmax(rint((double)v.x / s), -128.0), 127.0);
            As[row * 33 + q4 * 4 + 1] = (float)fmin(fmax(rint((double)v.y / s), -128.0), 127.0);
            As[row * 33 + q4 * 4 + 2] = (float)fmin(fmax(rint((double)v.z / s), -128.0), 127.0);
            As[row * 33 + q4 * 4 + 3] = (float)fmin(fmax(rint((double)v.w / s), -128.0), 127.0);
            int krow = slot >> 4, n4 = slot & 15;
            float4 w4 = *(const float4*)(Wf + (long)(k0 + krow) * 512 + n0 + n4 * 4);
            Bs[krow * 65 + n4 * 4 + 0] = w4.x;
            Bs[krow * 65 + n4 * 4 + 1] = w4.y;
            Bs[krow * 65 + n4 * 4 + 2] = w4.z;
            Bs[krow * 65 + n4 * 4 + 3] = w4.w;
        }
        __syncthreads();
        for (int kk = 0; kk < 32; ++kk) {
            float a[4], bb[4];
#pragma unroll
            for (int i = 0; i < 4; ++i) a[i] = As[(ty * 4 + i) * 33 + kk];
#pragma unroll
            for (int j = 0; j < 4; ++j) bb[j] = Bs[kk * 65 + tx * 4 + j];
#pragma unroll
            for (int i = 0; i < 4; ++i)
#pragma unroll
                for (int j = 0; j < 4; ++j) acc[i][j] += a[i] * bb[j];
        }
    }
#pragma unroll
    for (int i = 0; i < 4; ++i)
#pragma unroll
        for (int j = 0; j < 4; ++j) {
            int m = m0 + ty * 4 + i, n = n0 + tx * 4 + j;
            out[(long)m * 512 + n] = (float)((double)acc[i][j] * sx[m & 2047]);
        }
}

// ---------------------------------------------------------------------------
extern "C" void kernel_launch(void* const* d_in, const int* in_sizes, int n_in,
                              void* d_out, int out_size, void* d_ws, size_t ws_size,
                              hipStream_t stream)
{
    const float* query = (const float*)d_in[0];
    const float* key_  = (const float*)d_in[1];
    const float* value = (const float*)d_in[2];
    const float* Wq = (const float*)d_in[3];
    const float* Wk = (const float*)d_in[4];
    const float* Wv = (const float*)d_in[5];
    const float* Wf = (const float*)d_in[6];
    float* out = (float*)d_out;

    char* p = (char*)d_ws;
    auto alloc = [&](size_t bytes) -> char* {
        char* r = p;
        p += (bytes + 255) & ~(size_t)255;
        return r;
    };
    double*   sA   = (double*)alloc(3 * 2048 * 8);
    double*   sx   = (double*)alloc(2048 * 8);
    double*   sw   = (double*)alloc(3 * 512 * 8);
    _Float16* qW   = (_Float16*)alloc((size_t)3 * 512 * 512 * 2);
    double*   Qb   = (double*)alloc((size_t)2048 * 512 * 8);
    double*   Kb   = (double*)alloc((size_t)2048 * 512 * 8);
    double*   Vb   = (double*)alloc((size_t)2048 * 512 * 8);
    float*    xbuf = (float*)alloc((size_t)8192 * 512 * 4);

    token_scale<<<dim3(2048, 3), 256, 0, stream>>>(query, key_, value, sA);
    wquant<<<dim3(2, 3), 256, 0, stream>>>(Wq, Wk, Wv, sw, qW);
    for (int b = 0; b < 4; ++b) {
        proj_valu<<<dim3(32, 8, 3), 256, 0, stream>>>(query, key_, value, sA, qW, sw,
                                                      Qb, Kb, Vb, b);
        attn_fast<<<dim3(64, 8), 256, 0, stream>>>(Qb, Kb, Vb, xbuf, b);
    }
    token_scale<<<dim3(2048, 1), 256, 0, stream>>>(xbuf, xbuf, xbuf, sx);
    final_valu<<<dim3(128, 8), 256, 0, stream>>>(xbuf, sx, Wf, out);
}

// Round 9
// 1481.198 us; speedup vs baseline: 6.5158x; 1.6832x over previous
//
#include <hip/hip_runtime.h>
#include <math.h>

// ---------------------------------------------------------------------------
// Round 9: f64-MFMA attention with RUNTIME D-layout probe.
// R7/R8 failed identically (3440) -> deterministic logic error in the new
// MFMA path; prime suspect is the f64 D-row mapping (f32 family: 4*quad+reg;
// f64 may differ).  Two integer-exact probe MFMAs decode row/col per reg with
// NO layout assumptions (A=all-ones / B=all-ones are mapping-invariant):
//   D1 = MFMA(1, lane):  D1[i][j] = 4j + 96  -> col = (D1-96)/4
//   D2 = MFMA(lane, 1):  D2[i][j] = 4i + 96  -> row = (D2-96)/4
// All D-dependent indexing uses the probed values.  Numerics frozen at the
// green R5/R6 level (absmax 54.0): f64 quant decisions, f64 scores/softmax/
// PV; order-only changes.  B=4, T=2048, D=512, H=8, dk=64.  ws ~66 MB.
// ---------------------------------------------------------------------------

typedef double f64x4 __attribute__((ext_vector_type(4)));
#define MFMA_F64(a, b, c) __builtin_amdgcn_mfma_f64_16x16x4f64((a), (b), (c), 0, 0, 0)

// ---------------------------------------------------------------------------
// Kernel 1: per-token abs-max scale (f64 decisions).  UNCHANGED (green).
// ---------------------------------------------------------------------------
__global__ __launch_bounds__(256) void token_scale(
    const float* __restrict__ x0, const float* __restrict__ x1,
    const float* __restrict__ x2, double* __restrict__ out)
{
    const int t = blockIdx.x;
    const int z = blockIdx.y;
    const float* __restrict__ x = (z == 0) ? x0 : ((z == 1) ? x1 : x2);
    const int tid = threadIdx.x;
    float m = 0.0f;
#pragma unroll
    for (int i = 0; i < 2; ++i) {
        int f = i * 256 + tid;
        int b = f >> 7, d4 = f & 127;
        float4 v = *(const float4*)(x + (long)(b * 2048 + t) * 512 + d4 * 4);
        m = fmaxf(m, fmaxf(fmaxf(fabsf(v.x), fabsf(v.y)), fmaxf(fabsf(v.z), fabsf(v.w))));
    }
#pragma unroll
    for (int off = 1; off < 64; off <<= 1) m = fmaxf(m, __shfl_xor(m, off));
    __shared__ float red[4];
    if ((tid & 63) == 0) red[tid >> 6] = m;
    __syncthreads();
    if (tid == 0) {
        m = fmaxf(fmaxf(red[0], red[1]), fmaxf(red[2], red[3]));
        out[z * 2048 + t] = fmax((double)m / 127.0, 1e-8);
    }
}

// ---------------------------------------------------------------------------
// Kernel 2: weight quantization (f64 decisions).  UNCHANGED (green).
// ---------------------------------------------------------------------------
__global__ __launch_bounds__(256) void wquant(
    const float* __restrict__ Wq, const float* __restrict__ Wk,
    const float* __restrict__ Wv, double* __restrict__ sw,
    _Float16* __restrict__ qW)
{
    const int z = blockIdx.y;
    const float* __restrict__ W = (z == 0) ? Wq : (z == 1) ? Wk : Wv;
    const int col = blockIdx.x * 256 + threadIdx.x;
    float m = 0.0f;
    for (int k = 0; k < 512; ++k) m = fmaxf(m, fabsf(W[k * 512 + col]));
    const double s = fmax((double)m / 127.0, 1e-8);
    sw[z * 512 + col] = s;
    _Float16* q = qW + (long)z * 262144 + (long)col * 512;
    for (int k = 0; k < 512; ++k)
        q[k] = (_Float16)fmin(fmax(rint((double)W[k * 512 + col] / s), -128.0), 127.0);
}

// ---------------------------------------------------------------------------
// Kernel 3: projection GEMM (exact-int fp32, f64 decisions + dequant).
// UNCHANGED (green).
// ---------------------------------------------------------------------------
__global__ __launch_bounds__(256) void proj_valu(
    const float* __restrict__ q_in, const float* __restrict__ k_in,
    const float* __restrict__ v_in, const double* __restrict__ saAll,
    const _Float16* __restrict__ qW, const double* __restrict__ swAll,
    double* __restrict__ Qb, double* __restrict__ Kb, double* __restrict__ Vb,
    int b)
{
    const int z = blockIdx.z;
    const float* __restrict__ A = (z == 0) ? q_in : (z == 1) ? k_in : v_in;
    const double* __restrict__ sa = saAll + z * 2048;
    const _Float16* __restrict__ Bq = qW + (long)z * 262144;
    const double* __restrict__ swz = swAll + z * 512;
    double* __restrict__ O = (z == 0) ? Qb : (z == 1) ? Kb : Vb;

    const int m0 = blockIdx.x * 64, n0 = blockIdx.y * 64;
    const int tid = threadIdx.x, ty = tid >> 4, tx = tid & 15;

    __shared__ float As[64 * 33];
    __shared__ float Bs[64 * 33];

    float acc[4][4] = {{0.f,0.f,0.f,0.f},{0.f,0.f,0.f,0.f},
                       {0.f,0.f,0.f,0.f},{0.f,0.f,0.f,0.f}};

    for (int k0 = 0; k0 < 512; k0 += 32) {
        if (k0) __syncthreads();
#pragma unroll
        for (int i = 0; i < 2; ++i) {
            int slot = i * 256 + tid;
            int row = slot >> 3, q4 = slot & 7;
            int t = m0 + row;
            float4 v = *(const float4*)(A + ((long)(b * 2048 + t)) * 512 + k0 + q4 * 4);
            double s = sa[t];
            As[row * 33 + q4 * 4 + 0] = (float)fmin(fmax(rint((double)v.x / s), -128.0), 127.0);
            As[row * 33 + q4 * 4 + 1] = (float)fmin(fmax(rint((double)v.y / s), -128.0), 127.0);
            As[row * 33 + q4 * 4 + 2] = (float)fmin(fmax(rint((double)v.z / s), -128.0), 127.0);
            As[row * 33 + q4 * 4 + 3] = (float)fmin(fmax(rint((double)v.w / s), -128.0), 127.0);
            const _Float16* wp = Bq + (long)(n0 + row) * 512 + k0 + q4 * 4;
            Bs[row * 33 + q4 * 4 + 0] = (float)wp[0];
            Bs[row * 33 + q4 * 4 + 1] = (float)wp[1];
            Bs[row * 33 + q4 * 4 + 2] = (float)wp[2];
            Bs[row * 33 + q4 * 4 + 3] = (float)wp[3];
        }
        __syncthreads();
        for (int kk = 0; kk < 32; ++kk) {
            float a[4], bb[4];
#pragma unroll
            for (int i = 0; i < 4; ++i) a[i] = As[(ty * 4 + i) * 33 + kk];
#pragma unroll
            for (int j = 0; j < 4; ++j) bb[j] = Bs[(tx * 4 + j) * 33 + kk];
#pragma unroll
            for (int i = 0; i < 4; ++i)
#pragma unroll
                for (int j = 0; j < 4; ++j) acc[i][j] += a[i] * bb[j];
        }
    }
#pragma unroll
    for (int i = 0; i < 4; ++i)
#pragma unroll
        for (int j = 0; j < 4; ++j) {
            int t = m0 + ty * 4 + i, n = n0 + tx * 4 + j;
            double val = (double)acc[i][j] * sa[t] * swz[n];
            int h = n >> 6, d = n & 63;
            O[((long)h * 2048 + t) * 64 + d] = val;
        }
}

// ---------------------------------------------------------------------------
// Kernel 4: attention on the f64 matrix pipe, D-layout self-probing.
// grid (32 q-tiles of 64, 8 heads, 2 batch slots), block 256 (4 waves; wave w
// owns q-rows w*16..+15).  A/B operand mapping (universal CDNA 16x16):
// A[m=lane%16][k=lane/16], B[k=lane/16][n=lane%16].  D row/col PROBED.
// ---------------------------------------------------------------------------
__global__ __launch_bounds__(256) void attn_mfma(
    const double* __restrict__ Qb, const double* __restrict__ Kb,
    const double* __restrict__ Vb, float* __restrict__ xbuf, int bbase)
{
    const int q0 = blockIdx.x * 64;
    const int h = blockIdx.y;
    const int slot = blockIdx.z;
    const int b = bbase + slot;
    const double* __restrict__ Qp = Qb + (long)slot * (2048 * 512);
    const double* __restrict__ Kp = Kb + (long)slot * (2048 * 512);
    const double* __restrict__ Vp = Vb + (long)slot * (2048 * 512);

    const int tid = threadIdx.x;
    const int w = tid >> 6, lane = tid & 63;
    const int ln = lane & 15, quad = lane >> 4;

    __shared__ double Ks[32 * 65];
    __shared__ double Vs[32 * 65];
    __shared__ double SP[64 * 33];
    __shared__ double mS[64], lS[64], aS[64];
    __shared__ double psums[64 * 4];

    // ---- runtime D-layout probe (integer-exact, mapping-assumption-free) ----
    int rowp[4], colp[4];
    {
        const f64x4 z4 = {0.0, 0.0, 0.0, 0.0};
        double laned = (double)lane;
        f64x4 dcol = MFMA_F64(1.0, laned, z4);   // D[i][j] = 4j + 96
        f64x4 drow = MFMA_F64(laned, 1.0, z4);   // D[i][j] = 4i + 96
#pragma unroll
        for (int r = 0; r < 4; ++r) {
            colp[r] = (((int)dcol[r] - 96) >> 2) & 15;
            rowp[r] = (((int)drow[r] - 96) >> 2) & 15;
        }
    }

    // Q fragments pinned in registers: qreg[s] = Q[q0+w*16+ln][4s+quad]
    double qreg[16];
    {
        const double* qp = Qp + ((long)h * 2048 + q0 + w * 16 + ln) * 64 + quad;
#pragma unroll
        for (int s = 0; s < 16; ++s) qreg[s] = qp[4 * s];
    }
    if (tid < 64) { mS[tid] = -1.0e300; lS[tid] = 0.0; }

    f64x4 O[4];
#pragma unroll
    for (int dt = 0; dt < 4; ++dt) { O[dt][0] = 0; O[dt][1] = 0; O[dt][2] = 0; O[dt][3] = 0; }

    for (int k0 = 0; k0 < 2048; k0 += 32) {
        __syncthreads();  // B1: prior readers of Ks/Vs/SP done
        {
            int row = tid >> 3, d8 = (tid & 7) * 8;
            const double* kp = Kp + ((long)h * 2048 + k0 + row) * 64 + d8;
            const double* vp = Vp + ((long)h * 2048 + k0 + row) * 64 + d8;
#pragma unroll
            for (int j = 0; j < 4; ++j) {
                double2 kv = *(const double2*)(kp + 2 * j);
                double2 vv = *(const double2*)(vp + 2 * j);
                Ks[row * 65 + d8 + 2 * j]     = kv.x;
                Ks[row * 65 + d8 + 2 * j + 1] = kv.y;
                Vs[row * 65 + d8 + 2 * j]     = vv.x;
                Vs[row * 65 + d8 + 2 * j + 1] = vv.y;
            }
        }
        __syncthreads();  // B2: tiles visible

        // ---- S = QK^T (2 chains of 16 MFMA) ----
        f64x4 S0, S1;
        S0[0] = 0; S0[1] = 0; S0[2] = 0; S0[3] = 0;
        S1[0] = 0; S1[1] = 0; S1[2] = 0; S1[3] = 0;
#pragma unroll
        for (int s = 0; s < 16; ++s) {
            double b0 = Ks[(ln) * 65 + 4 * s + quad];
            double b1 = Ks[(16 + ln) * 65 + 4 * s + quad];
            S0 = MFMA_F64(qreg[s], b0, S0);
            S1 = MFMA_F64(qreg[s], b1, S1);
        }
#pragma unroll
        for (int r = 0; r < 4; ++r) {
            int gr = w * 16 + rowp[r];
            SP[gr * 33 + colp[r]] = S0[r] * 0.125;
            SP[gr * 33 + 16 + colp[r]] = S1[r] * 0.125;
        }
        __syncthreads();  // B3: S visible

        if (tid < 64) {
            double rm = -1.0e300;
            for (int k = 0; k < 32; ++k) rm = fmax(rm, SP[tid * 33 + k]);
            double mold = mS[tid];
            double mn = fmax(mold, rm);
            aS[tid] = exp(mold - mn);
            mS[tid] = mn;
        }
        __syncthreads();  // B4: stats visible

        {
            int row = tid >> 2, c0 = (tid & 3) * 8;
            double mn = mS[row];
            double sum = 0.0;
#pragma unroll
            for (int j = 0; j < 8; ++j) {
                double p = exp(SP[row * 33 + c0 + j] - mn);
                SP[row * 33 + c0 + j] = p;
                sum += p;
            }
            psums[row * 4 + (tid & 3)] = sum;
        }
#pragma unroll
        for (int r = 0; r < 4; ++r) {
            double a = aS[w * 16 + rowp[r]];
#pragma unroll
            for (int dt = 0; dt < 4; ++dt) O[dt][r] *= a;
        }
        __syncthreads();  // B5: P + psums visible

        if (tid < 64)
            lS[tid] = lS[tid] * aS[tid] +
                      (psums[tid * 4 + 0] + psums[tid * 4 + 1] +
                       psums[tid * 4 + 2] + psums[tid * 4 + 3]);

        // ---- PV (4 chains of 8 MFMA) ----
#pragma unroll
        for (int s = 0; s < 8; ++s) {
            double ap = SP[(w * 16 + ln) * 33 + 4 * s + quad];
#pragma unroll
            for (int dt = 0; dt < 4; ++dt) {
                double bv = Vs[(4 * s + quad) * 65 + dt * 16 + ln];
                O[dt] = MFMA_F64(ap, bv, O[dt]);
            }
        }
    }

    __syncthreads();  // final lS visible
#pragma unroll
    for (int r = 0; r < 4; ++r) {
        int row = w * 16 + rowp[r];
        double l = lS[row];
        long base = ((long)(b * 2048 + q0 + row)) * 512 + h * 64;
#pragma unroll
        for (int dt = 0; dt < 4; ++dt)
            xbuf[base + dt * 16 + colp[r]] = (float)(O[dt][r] / l);
    }
}

// ---------------------------------------------------------------------------
// Kernel 5: final GEMM (f64 decisions, exact-int fp32 GEMM).  UNCHANGED.
// ---------------------------------------------------------------------------
__global__ __launch_bounds__(256) void final_valu(
    const float* __restrict__ xbuf, const double* __restrict__ sx,
    const float* __restrict__ Wf, float* __restrict__ out)
{
    const int m0 = blockIdx.x * 64, n0 = blockIdx.y * 64;
    const int tid = threadIdx.x, ty = tid >> 4, tx = tid & 15;

    __shared__ float As[64 * 33];
    __shared__ float Bs[32 * 65];

    float acc[4][4] = {{0.f,0.f,0.f,0.f},{0.f,0.f,0.f,0.f},
                       {0.f,0.f,0.f,0.f},{0.f,0.f,0.f,0.f}};

    for (int k0 = 0; k0 < 512; k0 += 32) {
        if (k0) __syncthreads();
#pragma unroll
        for (int i = 0; i < 2; ++i) {
            int slot = i * 256 + tid;
            int row = slot >> 3, q4 = slot & 7;
            int m = m0 + row;
            double s = sx[m & 2047];
            float4 v = *(const float4*)(xbuf + (long)m * 512 + k0 + q4 * 4);
            As[row * 33 + q4 * 4 + 0] = (float)fmin(fmax(rint((double)v.x / s), -128.0), 127.0);
            As[row * 33 + q4 * 4 + 1] = (float)fmin(fmax(rint((double)v.y / s), -128.0), 127.0);
            As[row * 33 + q4 * 4 + 2] = (float)fmin(fmax(rint((double)v.z / s), -128.0), 127.0);
            As[row * 33 + q4 * 4 + 3] = (float)fmin(fmax(rint((double)v.w / s), -128.0), 127.0);
            int krow = slot >> 4, n4 = slot & 15;
            float4 w4 = *(const float4*)(Wf + (long)(k0 + krow) * 512 + n0 + n4 * 4);
            Bs[krow * 65 + n4 * 4 + 0] = w4.x;
            Bs[krow * 65 + n4 * 4 + 1] = w4.y;
            Bs[krow * 65 + n4 * 4 + 2] = w4.z;
            Bs[krow * 65 + n4 * 4 + 3] = w4.w;
        }
        __syncthreads();
        for (int kk = 0; kk < 32; ++kk) {
            float a[4], bb[4];
#pragma unroll
            for (int i = 0; i < 4; ++i) a[i] = As[(ty * 4 + i) * 33 + kk];
#pragma unroll
            for (int j = 0; j < 4; ++j) bb[j] = Bs[kk * 65 + tx * 4 + j];
#pragma unroll
            for (int i = 0; i < 4; ++i)
#pragma unroll
                for (int j = 0; j < 4; ++j) acc[i][j] += a[i] * bb[j];
        }
    }
#pragma unroll
    for (int i = 0; i < 4; ++i)
#pragma unroll
        for (int j = 0; j < 4; ++j) {
            int m = m0 + ty * 4 + i, n = n0 + tx * 4 + j;
            out[(long)m * 512 + n] = (float)((double)acc[i][j] * sx[m & 2047]);
        }
}

// ---------------------------------------------------------------------------
extern "C" void kernel_launch(void* const* d_in, const int* in_sizes, int n_in,
                              void* d_out, int out_size, void* d_ws, size_t ws_size,
                              hipStream_t stream)
{
    const float* query = (const float*)d_in[0];
    const float* key_  = (const float*)d_in[1];
    const float* value = (const float*)d_in[2];
    const float* Wq = (const float*)d_in[3];
    const float* Wk = (const float*)d_in[4];
    const float* Wv = (const float*)d_in[5];
    const float* Wf = (const float*)d_in[6];
    float* out = (float*)d_out;

    // workspace carve-up: ~66 MB
    char* p = (char*)d_ws;
    auto alloc = [&](size_t bytes) -> char* {
        char* r = p;
        p += (bytes + 255) & ~(size_t)255;
        return r;
    };
    double*   sA   = (double*)alloc(3 * 2048 * 8);
    double*   sx   = (double*)alloc(2048 * 8);
    double*   sw   = (double*)alloc(3 * 512 * 8);
    _Float16* qW   = (_Float16*)alloc((size_t)3 * 512 * 512 * 2);
    const size_t plane = (size_t)2048 * 512;
    double*   Qb   = (double*)alloc(2 * plane * 8);
    double*   Kb   = (double*)alloc(2 * plane * 8);
    double*   Vb   = (double*)alloc(2 * plane * 8);
    float*    xbuf = (float*)alloc((size_t)8192 * 512 * 4);

    token_scale<<<dim3(2048, 3), 256, 0, stream>>>(query, key_, value, sA);
    wquant<<<dim3(2, 3), 256, 0, stream>>>(Wq, Wk, Wv, sw, qW);
    for (int pair = 0; pair < 2; ++pair) {
        proj_valu<<<dim3(32, 8, 3), 256, 0, stream>>>(query, key_, value, sA, qW, sw,
                                                      Qb, Kb, Vb, pair * 2);
        proj_valu<<<dim3(32, 8, 3), 256, 0, stream>>>(query, key_, value, sA, qW, sw,
                                                      Qb + plane, Kb + plane, Vb + plane,
                                                      pair * 2 + 1);
        attn_mfma<<<dim3(32, 8, 2), 256, 0, stream>>>(Qb, Kb, Vb, xbuf, pair * 2);
    }
    token_scale<<<dim3(2048, 1), 256, 0, stream>>>(xbuf, xbuf, xbuf, sx);
    final_valu<<<dim3(128, 8), 256, 0, stream>>>(xbuf, sx, Wf, out);
}